// Round 4
// baseline (563.766 us; speedup 1.0000x reference)
//
#include <hip/hip_runtime.h>

#define NBINS 256
#define NCH 3
#define HSIZE (NBINS * NCH)   // 768
#define NWAVE 4               // private histogram copies per block (one per wave)
#define SLOTS 8               // global partial-histogram copies
#define TPB 256
#define BLOCKS 2048

typedef float f4 __attribute__((ext_vector_type(4)));

// ws layout: [SLOTS * HSIZE] u32 partial counts, then [1] u32 done-counter.
__global__ __launch_bounds__(TPB) void hist_kernel(const float* __restrict__ in,
                                                   unsigned int* __restrict__ ws,
                                                   float* __restrict__ out,
                                                   int n, float inv_total) {
    __shared__ unsigned int lds[NWAVE][HSIZE];
    __shared__ int is_last;

    const int tid = threadIdx.x;

    // zero LDS (3072 words / 256 threads = 12 each)
    unsigned int* flat = &lds[0][0];
    #pragma unroll
    for (int i = 0; i < NWAVE * HSIZE / TPB; ++i)
        flat[tid + i * TPB] = 0u;
    __syncthreads();

    unsigned int* h = lds[tid >> 6];

    // Each thread owns groups of 12 consecutive floats (= 4 RGB pixels = 3 float4).
    // Group base element 12*g is always channel 0 -> channel pattern is STATIC:
    //   f4 a (elems 0..3):  ch 0,1,2,0
    //   f4 b (elems 4..7):  ch 1,2,0,1
    //   f4 c (elems 8..11): ch 2,0,1,2
    const long long ngrp   = n / 12;
    const long long stride = (long long)gridDim.x * TPB;
    const f4* __restrict__ in4 = (const f4*)in;

    #pragma unroll 2
    for (long long g = (long long)blockIdx.x * TPB + tid; g < ngrp; g += stride) {
        const f4* p = in4 + 3 * g;
        f4 a = p[0];
        f4 b = p[1];
        f4 c = p[2];

        int a0 = min(max((int)(a.x * 256.0f), 0), 255);
        int a1 = min(max((int)(a.y * 256.0f), 0), 255);
        int a2 = min(max((int)(a.z * 256.0f), 0), 255);
        int a3 = min(max((int)(a.w * 256.0f), 0), 255);
        int b0 = min(max((int)(b.x * 256.0f), 0), 255);
        int b1 = min(max((int)(b.y * 256.0f), 0), 255);
        int b2 = min(max((int)(b.z * 256.0f), 0), 255);
        int b3 = min(max((int)(b.w * 256.0f), 0), 255);
        int c0 = min(max((int)(c.x * 256.0f), 0), 255);
        int c1 = min(max((int)(c.y * 256.0f), 0), 255);
        int c2 = min(max((int)(c.z * 256.0f), 0), 255);
        int c3 = min(max((int)(c.w * 256.0f), 0), 255);

        atomicAdd(&h[0 * NBINS + a0], 1u);
        atomicAdd(&h[1 * NBINS + a1], 1u);
        atomicAdd(&h[2 * NBINS + a2], 1u);
        atomicAdd(&h[0 * NBINS + a3], 1u);
        atomicAdd(&h[1 * NBINS + b0], 1u);
        atomicAdd(&h[2 * NBINS + b1], 1u);
        atomicAdd(&h[0 * NBINS + b2], 1u);
        atomicAdd(&h[1 * NBINS + b3], 1u);
        atomicAdd(&h[2 * NBINS + c0], 1u);
        atomicAdd(&h[0 * NBINS + c1], 1u);
        atomicAdd(&h[1 * NBINS + c2], 1u);
        atomicAdd(&h[2 * NBINS + c3], 1u);
    }

    // scalar tail (n not divisible by 12) — only block 0
    if (blockIdx.x == 0) {
        for (long long e = ngrp * 12 + tid; e < n; e += TPB) {
            float x = in[e];
            int bin = min(max((int)(x * 256.0f), 0), 255);
            int ch = (int)(e % 3);
            atomicAdd(&h[ch * NBINS + bin], 1u);
        }
    }

    __syncthreads();

    // flush: sum the 4 wave copies, one global atomic per bin per block,
    // spread over 8 slots to cap per-address contention at 256 adders.
    unsigned int* dst = ws + (blockIdx.x & (SLOTS - 1)) * HSIZE;
    #pragma unroll
    for (int i = 0; i < HSIZE / TPB; ++i) {
        int idx = tid + i * TPB;
        unsigned int s = lds[0][idx] + lds[1][idx] + lds[2][idx] + lds[3][idx];
        if (s) atomicAdd(&dst[idx], s);
    }

    // last-block-done: the final block to finish performs the finalize,
    // saving a separate kernel launch.
    __threadfence();                       // release our slot atomics
    if (tid == 0) {
        unsigned int prev = atomicAdd(&ws[SLOTS * HSIZE], 1u);
        is_last = (prev == (unsigned int)(gridDim.x - 1));
    }
    __syncthreads();

    if (is_last) {
        __threadfence();                   // acquire all blocks' slot atomics
        #pragma unroll
        for (int i = 0; i < HSIZE / TPB; ++i) {
            int idx = tid + i * TPB;       // idx = c*256 + bin
            unsigned int s = 0;
            #pragma unroll
            for (int k = 0; k < SLOTS; ++k)
                s += atomicAdd(&ws[k * HSIZE + idx], 0u);   // coherent read
            int c = idx >> 8, bin = idx & 255;
            out[bin * 3 + c] = (float)s * inv_total;        // out: [bin, channel]
        }
    }
}

extern "C" void kernel_launch(void* const* d_in, const int* in_sizes, int n_in,
                              void* d_out, int out_size, void* d_ws, size_t ws_size,
                              hipStream_t stream) {
    const float* in = (const float*)d_in[0];
    const int n = in_sizes[0];
    unsigned int* ws = (unsigned int*)d_ws;

    // zero SLOTS partial histograms + the done-counter (24 KB + 4 B)
    hipMemsetAsync(ws, 0, (SLOTS * HSIZE + 1) * sizeof(unsigned int), stream);
    hist_kernel<<<BLOCKS, TPB, 0, stream>>>(in, ws, (float*)d_out, n,
                                            1.0f / (float)(n / NCH));
}

// Round 5
// 268.860 us; speedup vs baseline: 2.0969x; 2.0969x over previous
//
#include <hip/hip_runtime.h>

#define NBINS 256
#define NCH 3
#define HSIZE (NBINS * NCH)   // 768
#define NWAVE 4               // waves per block (256 threads)
#define SLOTS 8               // global partial-histogram copies
#define TPB 256
#define BLOCKS 2048

__global__ __launch_bounds__(TPB) void hist_kernel(const float* __restrict__ in,
                                                   unsigned int* __restrict__ ws,
                                                   int n) {
    __shared__ unsigned int lds[NWAVE][HSIZE];

    const int tid = threadIdx.x;
    const int wave = tid >> 6;

    // zero LDS (3072 words / 256 threads = 12 each)
    unsigned int* flat = &lds[0][0];
    #pragma unroll
    for (int i = 0; i < NWAVE * HSIZE / TPB; ++i)
        flat[tid + i * TPB] = 0u;
    __syncthreads();

    unsigned int* h = lds[wave];

    const int n4 = n >> 2;                               // float4 count
    const long long gtid    = (long long)blockIdx.x * TPB + tid;
    const long long stride4 = (long long)gridDim.x * TPB;
    const float4* __restrict__ in4 = (const float4*)in;

    // channel of element 4*i: (4*i) % 3 == i % 3  (4 ≡ 1 mod 3)
    int m  = (int)(gtid % 3);
    const int ms = (int)(stride4 % 3);

    for (long long i = gtid; i < n4; i += stride4) {
        float4 v = in4[i];
        // channels: m, m+1, m+2, m  (mod 3)
        int c0 = m;
        int c1 = m + 1; if (c1 >= 3) c1 -= 3;
        int c2 = m + 2; if (c2 >= 3) c2 -= 3;

        int b0 = (int)(v.x * 256.0f); b0 = min(max(b0, 0), 255);
        int b1 = (int)(v.y * 256.0f); b1 = min(max(b1, 0), 255);
        int b2 = (int)(v.z * 256.0f); b2 = min(max(b2, 0), 255);
        int b3 = (int)(v.w * 256.0f); b3 = min(max(b3, 0), 255);

        atomicAdd(&h[c0 * NBINS + b0], 1u);
        atomicAdd(&h[c1 * NBINS + b1], 1u);
        atomicAdd(&h[c2 * NBINS + b2], 1u);
        atomicAdd(&h[c0 * NBINS + b3], 1u);   // elem 3 has channel m again
        m += ms; if (m >= 3) m -= 3;
    }

    // scalar tail (n not divisible by 4) — only block 0
    if (blockIdx.x == 0) {
        for (int e = (n4 << 2) + tid; e < n; e += TPB) {
            float x = in[e];
            int b = (int)(x * 256.0f); b = min(max(b, 0), 255);
            int c = e % 3;
            atomicAdd(&h[c * NBINS + b], 1u);
        }
    }

    __syncthreads();

    // flush: sum the 4 wave copies, one global atomic per bin per block
    unsigned int* dst = ws + (blockIdx.x & (SLOTS - 1)) * HSIZE;
    #pragma unroll
    for (int i = 0; i < HSIZE / TPB; ++i) {
        int idx = tid + i * TPB;
        unsigned int s = lds[0][idx] + lds[1][idx] + lds[2][idx] + lds[3][idx];
        if (s) atomicAdd(&dst[idx], s);
    }
}

__global__ void finalize_kernel(const unsigned int* __restrict__ ws,
                                float* __restrict__ out,
                                float total) {
    int t = threadIdx.x;          // 0..767
    int bin = t / 3;
    int c = t - 3 * bin;
    unsigned int s = 0;
    #pragma unroll
    for (int k = 0; k < SLOTS; ++k)
        s += ws[k * HSIZE + c * NBINS + bin];
    out[t] = (float)s / total;    // out layout: [bin, channel]
}

extern "C" void kernel_launch(void* const* d_in, const int* in_sizes, int n_in,
                              void* d_out, int out_size, void* d_ws, size_t ws_size,
                              hipStream_t stream) {
    const float* in = (const float*)d_in[0];
    const int n = in_sizes[0];
    unsigned int* ws = (unsigned int*)d_ws;

    hipMemsetAsync(ws, 0, SLOTS * HSIZE * sizeof(unsigned int), stream);
    hist_kernel<<<BLOCKS, TPB, 0, stream>>>(in, ws, n);
    finalize_kernel<<<1, HSIZE, 0, stream>>>(ws, (float*)d_out, (float)(n / NCH));
}